// Round 4
// baseline (833.923 us; speedup 1.0000x reference)
//
#include <hip/hip_runtime.h>
#include <math.h>

#define NN 100000
#define NE 1600000
#define DF 256
#define HH 64
#define TT 4
#define GG 8
#define BN_EPS 1e-5f

#define SCAN_BLK 1024
#define NB_SCAN ((NN + SCAN_BLK - 1) / SCAN_BLK)   // 98

typedef __attribute__((ext_vector_type(8))) short short8v;
typedef __attribute__((ext_vector_type(4))) float f32x4;
typedef unsigned short ushort_t;
typedef unsigned int uint_t;

__device__ __forceinline__ void atomicMaxF(float* addr, float val) {
  if (val >= 0.f) atomicMax((int*)addr, __float_as_int(val));
  else            atomicMin((unsigned int*)addr, __float_as_uint(val));
}

// fp32 -> bf16 bits, round-to-nearest-even
__device__ __forceinline__ short f2bf(float f) {
  uint_t u = __float_as_uint(f);
  u += 0x7FFFu + ((u >> 16) & 1u);
  return (short)(u >> 16);
}
// bf16 pair unpack from uint
__device__ __forceinline__ float bflo(uint_t u) { return __uint_as_float(u << 16); }
__device__ __forceinline__ float bfhi(uint_t u) { return __uint_as_float(u & 0xFFFF0000u); }

// ---------------- init: stats=0, max buffers=-inf ----------------
__global__ void k_init(float* __restrict__ stats, float* __restrict__ maxb) {
  int i = threadIdx.x;
  if (i < 512) stats[i] = 0.f;
  if (i < 64)  maxb[i]  = -INFINITY;
}

// ---------------- prep: fp32 -> bf16 bits ----------------
__global__ void k_prep(const float* __restrict__ W, ushort_t* __restrict__ Wbf, int n) {
  int i = blockIdx.x * 256 + threadIdx.x;
  if (i < n) Wbf[i] = (ushort_t)f2bf(W[i]);
}

// ---------------- GEMM1 (MFMA bf16): h1 = x @ W_first + b, + BN stats ----------------
__global__ __launch_bounds__(256, 2) void k_gemm1_mfma(
    const float* __restrict__ x, const ushort_t* __restrict__ Wbf,
    const float* __restrict__ b, float* __restrict__ h1,
    float* __restrict__ stats) {
  const int lane = threadIdx.x & 63;
  const int li = lane & 15;
  const int lh = lane >> 4;
  const int gw = (blockIdx.x * 256 + (int)threadIdx.x) >> 6;
  const int nw = (gridDim.x * 256) >> 6;

  short8v bf[8][4];
#pragma unroll
  for (int s = 0; s < 8; ++s)
#pragma unroll
    for (int ct = 0; ct < 4; ++ct)
#pragma unroll
      for (int e = 0; e < 8; ++e)
        bf[s][ct][e] = (short)Wbf[(32 * s + 8 * lh + e) * HH + ct * 16 + li];

  float bias[4];
#pragma unroll
  for (int ct = 0; ct < 4; ++ct) bias[ct] = b[ct * 16 + li];

  float ps[4] = {0.f, 0.f, 0.f, 0.f}, pss[4] = {0.f, 0.f, 0.f, 0.f};

  for (int t = gw; t < NN / 16; t += nw) {
    const float* xb = x + (size_t)(t * 16 + li) * DF + 8 * lh;
    f32x4 acc[4];
#pragma unroll
    for (int ct = 0; ct < 4; ++ct) acc[ct] = (f32x4){0.f, 0.f, 0.f, 0.f};

#pragma unroll
    for (int s = 0; s < 8; ++s) {
      float4 a0 = *(const float4*)(xb + 32 * s);
      float4 a1 = *(const float4*)(xb + 32 * s + 4);
      short8v af;
      af[0] = f2bf(a0.x); af[1] = f2bf(a0.y); af[2] = f2bf(a0.z); af[3] = f2bf(a0.w);
      af[4] = f2bf(a1.x); af[5] = f2bf(a1.y); af[6] = f2bf(a1.z); af[7] = f2bf(a1.w);
#pragma unroll
      for (int ct = 0; ct < 4; ++ct)
        acc[ct] = __builtin_amdgcn_mfma_f32_16x16x32_bf16(af, bf[s][ct], acc[ct], 0, 0, 0);
    }

    float* hb = h1 + (size_t)t * 16 * HH;
#pragma unroll
    for (int ct = 0; ct < 4; ++ct) {
#pragma unroll
      for (int r = 0; r < 4; ++r) {
        float h = acc[ct][r] + bias[ct];
        hb[(lh * 4 + r) * HH + ct * 16 + li] = h;
        ps[ct] += h; pss[ct] += h * h;
      }
    }
  }

#pragma unroll
  for (int ct = 0; ct < 4; ++ct) {
    ps[ct]  += __shfl_xor(ps[ct], 16);  ps[ct]  += __shfl_xor(ps[ct], 32);
    pss[ct] += __shfl_xor(pss[ct], 16); pss[ct] += __shfl_xor(pss[ct], 32);
  }
  if (lane < 16) {
#pragma unroll
    for (int ct = 0; ct < 4; ++ct) {
      atomicAdd(&stats[ct * 16 + lane], ps[ct]);
      atomicAdd(&stats[HH + ct * 16 + lane], pss[ct]);
    }
  }
}

// ---------------- BN finalize ----------------
__global__ void k_finalize_bn(const float* __restrict__ sums,
                              const float* __restrict__ gamma,
                              const float* __restrict__ beta,
                              float* __restrict__ ab) {
  int c = threadIdx.x;                                // 64 threads
  float mu  = sums[c] * (1.f / NN);
  float var = sums[HH + c] * (1.f / NN) - mu * mu;
  float a = gamma[c] * rsqrtf(var + BN_EPS);
  ab[c] = a;
  ab[HH + c] = beta[c] - mu * a;
}

// ---------------- normalize+ReLU + head (64->4) + graph max-pool ----------------
// WRITEF: emit f as bf16 (layer 0). ADDOUT: accumulate node_pred (layer 1).
template <int WRITEF, int ADDOUT>
__global__ __launch_bounds__(256) void k_norm_np(
    const float* __restrict__ hin, ushort_t* __restrict__ fout,
    const float* __restrict__ ab, const float* __restrict__ Wlin,
    const float* __restrict__ blin, const int* __restrict__ batch,
    float* __restrict__ node_pred, float* __restrict__ maxbuf, int rpb) {
  __shared__ float lmax[GG * TT];
  if (threadIdx.x < GG * TT) lmax[threadIdx.x] = -INFINITY;
  __syncthreads();

  const int lane = threadIdx.x & 63;
  const int wid  = threadIdx.x >> 6;
  const float a  = ab[lane];
  const float b2 = ab[HH + lane];
  const float4 w = ((const float4*)Wlin)[lane];       // W[lane][0..3]
  const float4 bl = *(const float4*)blin;
  int r0 = blockIdx.x * rpb;
  int r1 = min(r0 + rpb, NN);

  for (int r = r0 + wid; r < r1; r += 4) {
    float h = hin[(size_t)r * HH + lane];
    float f = fmaxf(fmaf(a, h, b2), 0.f);
    if (WRITEF) fout[(size_t)r * HH + lane] = (ushort_t)f2bf(f);
    float p0 = f * w.x, p1 = f * w.y, p2 = f * w.z, p3 = f * w.w;
#pragma unroll
    for (int off = 32; off; off >>= 1) {
      p0 += __shfl_xor(p0, off);
      p1 += __shfl_xor(p1, off);
      p2 += __shfl_xor(p2, off);
      p3 += __shfl_xor(p3, off);
    }
    if (lane == 0) {
      float4 np;
      np.x = p0 + bl.x; np.y = p1 + bl.y; np.z = p2 + bl.z; np.w = p3 + bl.w;
      int g = batch[r];
      atomicMaxF(&lmax[g * TT + 0], np.x);
      atomicMaxF(&lmax[g * TT + 1], np.y);
      atomicMaxF(&lmax[g * TT + 2], np.z);
      atomicMaxF(&lmax[g * TT + 3], np.w);
      float4* op = (float4*)(node_pred + (size_t)r * TT);
      if (ADDOUT) {
        float4 o = *op;
        np.x += o.x; np.y += o.y; np.z += o.z; np.w += o.w;
      }
      *op = np;
    }
  }
  __syncthreads();
  if (threadIdx.x < GG * TT) atomicMaxF(&maxbuf[threadIdx.x], lmax[threadIdx.x]);
}

// ---------------- CSR build: histogram ----------------
__global__ __launch_bounds__(256) void k_count(const int* __restrict__ ei,
                                               int* __restrict__ deg) {
  int i = blockIdx.x * blockDim.x + threadIdx.x;
  int n = gridDim.x * blockDim.x;
  for (int e = i; e < NE; e += n) atomicAdd(&deg[ei[NE + e]], 1);
}

// ---------------- CSR build: 3-kernel exclusive scan ----------------
__global__ __launch_bounds__(256) void k_scanA(const int* __restrict__ deg,
                                               int* __restrict__ rowstart,
                                               int* __restrict__ bsum) {
  __shared__ int s[256];
  int t = threadIdx.x;
  int base = blockIdx.x * SCAN_BLK + t * 4;
  int d0 = 0, d1 = 0, d2 = 0, d3 = 0;
  if (base + 3 < NN) {
    int4 v = *(const int4*)(deg + base);
    d0 = v.x; d1 = v.y; d2 = v.z; d3 = v.w;
  } else {
    if (base + 0 < NN) d0 = deg[base + 0];
    if (base + 1 < NN) d1 = deg[base + 1];
    if (base + 2 < NN) d2 = deg[base + 2];
    if (base + 3 < NN) d3 = deg[base + 3];
  }
  int ts = d0 + d1 + d2 + d3;
  s[t] = ts;
  __syncthreads();
  for (int off = 1; off < 256; off <<= 1) {
    int v = (t >= off) ? s[t - off] : 0;
    __syncthreads();
    s[t] += v;
    __syncthreads();
  }
  int excl = s[t] - ts;                  // block-local exclusive prefix
  if (base + 0 < NN) rowstart[base + 0] = excl;  excl += d0;
  if (base + 1 < NN) rowstart[base + 1] = excl;  excl += d1;
  if (base + 2 < NN) rowstart[base + 2] = excl;  excl += d2;
  if (base + 3 < NN) rowstart[base + 3] = excl;
  if (t == 255) bsum[blockIdx.x] = s[255];
}

__global__ void k_scanB(const int* __restrict__ bsum, int* __restrict__ bscan) {
  __shared__ int s[128];
  int t = threadIdx.x;                   // 128 threads
  int v = (t < NB_SCAN) ? bsum[t] : 0;
  s[t] = v;
  __syncthreads();
  for (int off = 1; off < 128; off <<= 1) {
    int u = (t >= off) ? s[t - off] : 0;
    __syncthreads();
    s[t] += u;
    __syncthreads();
  }
  if (t < NB_SCAN) bscan[t] = s[t] - v;
}

__global__ __launch_bounds__(256) void k_scanC(int* __restrict__ rowstart,
                                               const int* __restrict__ bscan,
                                               int* __restrict__ cursor) {
  int off = bscan[blockIdx.x];
  int base = blockIdx.x * SCAN_BLK + threadIdx.x * 4;
#pragma unroll
  for (int j = 0; j < 4; ++j) {
    int i = base + j;
    if (i < NN) {
      int r = rowstart[i] + off;
      rowstart[i] = r;
      cursor[i] = r;
    }
  }
}

// ---------------- CSR build: fill src lists ----------------
__global__ __launch_bounds__(256) void k_fill(const int* __restrict__ ei,
                                              int* __restrict__ cursor,
                                              int* __restrict__ srcl) {
  int i = blockIdx.x * blockDim.x + threadIdx.x;
  int n = gridDim.x * blockDim.x;
  for (int e = i; e < NE; e += n) {
    int src = ei[e];
    int dst = ei[NE + e];
    int p = atomicAdd(&cursor[dst], 1);
    srcl[p] = src;
  }
}

// ---------------- GEMM2 (MFMA bf16): g = f @ W_conv (no bias), bf16 out ----------------
__global__ __launch_bounds__(256) void k_gemm2_mfma(
    const ushort_t* __restrict__ fbf, const ushort_t* __restrict__ Wbf2,
    ushort_t* __restrict__ g) {
  const int lane = threadIdx.x & 63;
  const int li = lane & 15;
  const int lh = lane >> 4;
  const int gw = (blockIdx.x * 256 + (int)threadIdx.x) >> 6;
  const int nw = (gridDim.x * 256) >> 6;

  short8v bfr[2][4];
#pragma unroll
  for (int s = 0; s < 2; ++s)
#pragma unroll
    for (int ct = 0; ct < 4; ++ct)
#pragma unroll
      for (int e = 0; e < 8; ++e)
        bfr[s][ct][e] = (short)Wbf2[(32 * s + 8 * lh + e) * HH + ct * 16 + li];

  for (int t = gw; t < NN / 16; t += nw) {
    const ushort_t* fb = fbf + (size_t)(t * 16 + li) * HH + 8 * lh;
    short8v a0 = *(const short8v*)(fb);
    short8v a1 = *(const short8v*)(fb + 32);
    f32x4 acc[4];
#pragma unroll
    for (int ct = 0; ct < 4; ++ct) {
      acc[ct] = (f32x4){0.f, 0.f, 0.f, 0.f};
      acc[ct] = __builtin_amdgcn_mfma_f32_16x16x32_bf16(a0, bfr[0][ct], acc[ct], 0, 0, 0);
      acc[ct] = __builtin_amdgcn_mfma_f32_16x16x32_bf16(a1, bfr[1][ct], acc[ct], 0, 0, 0);
    }
    ushort_t* gb = g + (size_t)t * 16 * HH;
#pragma unroll
    for (int ct = 0; ct < 4; ++ct)
#pragma unroll
      for (int r = 0; r < 4; ++r)
        gb[(lh * 4 + r) * HH + ct * 16 + li] = (ushort_t)f2bf(acc[ct][r]);
  }
}

// ---------------- aggregate: h2[r] = b + g[r] + sum g[src], + BN stats ----------------
// quarter-wave per row: 16 lanes x uint2 (4 bf16 cols each); 4 rows per wave.
__global__ __launch_bounds__(256) void k_agg(
    const ushort_t* __restrict__ g, const int* __restrict__ rowstart,
    const int* __restrict__ deg, const int* __restrict__ srcl,
    const float* __restrict__ bias, float* __restrict__ h2,
    float* __restrict__ stats) {
  const int lane = threadIdx.x & 63;
  const int q  = lane >> 4;
  const int ql = lane & 15;
  const int gw = (blockIdx.x * 256 + (int)threadIdx.x) >> 6;
  const int nw = (gridDim.x * 256) >> 6;
  const float4 bb = ((const float4*)bias)[ql];

  float ps0 = 0.f, ps1 = 0.f, ps2 = 0.f, ps3 = 0.f;
  float pq0 = 0.f, pq1 = 0.f, pq2 = 0.f, pq3 = 0.f;

  for (int rb = gw * 4; rb < NN; rb += nw * 4) {
    int row = rb + q;
    const ushort_t* gq = g + ql * 4;
    uint2 sv = *(const uint2*)(gq + (size_t)row * HH);
    float a0 = bb.x + bflo(sv.x);
    float a1 = bb.y + bfhi(sv.x);
    float a2 = bb.z + bflo(sv.y);
    float a3 = bb.w + bfhi(sv.y);
    int s0 = rowstart[row], d = deg[row];
    int e = 0;
    for (; e + 4 <= d; e += 4) {
      int i0 = srcl[s0 + e + 0];
      int i1 = srcl[s0 + e + 1];
      int i2 = srcl[s0 + e + 2];
      int i3 = srcl[s0 + e + 3];
      uint2 v0 = *(const uint2*)(gq + (size_t)i0 * HH);
      uint2 v1 = *(const uint2*)(gq + (size_t)i1 * HH);
      uint2 v2 = *(const uint2*)(gq + (size_t)i2 * HH);
      uint2 v3 = *(const uint2*)(gq + (size_t)i3 * HH);
      a0 += bflo(v0.x) + bflo(v1.x) + bflo(v2.x) + bflo(v3.x);
      a1 += bfhi(v0.x) + bfhi(v1.x) + bfhi(v2.x) + bfhi(v3.x);
      a2 += bflo(v0.y) + bflo(v1.y) + bflo(v2.y) + bflo(v3.y);
      a3 += bfhi(v0.y) + bfhi(v1.y) + bfhi(v2.y) + bfhi(v3.y);
    }
    for (; e < d; ++e) {
      int i0 = srcl[s0 + e];
      uint2 v = *(const uint2*)(gq + (size_t)i0 * HH);
      a0 += bflo(v.x); a1 += bfhi(v.x); a2 += bflo(v.y); a3 += bfhi(v.y);
    }
    float4 o; o.x = a0; o.y = a1; o.z = a2; o.w = a3;
    *(float4*)(h2 + (size_t)row * HH + ql * 4) = o;
    ps0 += a0; ps1 += a1; ps2 += a2; ps3 += a3;
    pq0 += a0 * a0; pq1 += a1 * a1; pq2 += a2 * a2; pq3 += a3 * a3;
  }

  ps0 += __shfl_xor(ps0, 16); ps0 += __shfl_xor(ps0, 32);
  ps1 += __shfl_xor(ps1, 16); ps1 += __shfl_xor(ps1, 32);
  ps2 += __shfl_xor(ps2, 16); ps2 += __shfl_xor(ps2, 32);
  ps3 += __shfl_xor(ps3, 16); ps3 += __shfl_xor(ps3, 32);
  pq0 += __shfl_xor(pq0, 16); pq0 += __shfl_xor(pq0, 32);
  pq1 += __shfl_xor(pq1, 16); pq1 += __shfl_xor(pq1, 32);
  pq2 += __shfl_xor(pq2, 16); pq2 += __shfl_xor(pq2, 32);
  pq3 += __shfl_xor(pq3, 16); pq3 += __shfl_xor(pq3, 32);
  if (lane < 16) {
    atomicAdd(&stats[lane * 4 + 0], ps0);
    atomicAdd(&stats[lane * 4 + 1], ps1);
    atomicAdd(&stats[lane * 4 + 2], ps2);
    atomicAdd(&stats[lane * 4 + 3], ps3);
    atomicAdd(&stats[HH + lane * 4 + 0], pq0);
    atomicAdd(&stats[HH + lane * 4 + 1], pq1);
    atomicAdd(&stats[HH + lane * 4 + 2], pq2);
    atomicAdd(&stats[HH + lane * 4 + 3], pq3);
  }
}

// ---------------- final: wsi = max0 + max1 ----------------
__global__ void k_wsi(const float* __restrict__ m0, const float* __restrict__ m1,
                      float* __restrict__ out) {
  int i = threadIdx.x;                                // 32 threads
  out[i] = m0[i] + m1[i];
}

extern "C" void kernel_launch(void* const* d_in, const int* in_sizes, int n_in,
                              void* d_out, int out_size, void* d_ws, size_t ws_size,
                              hipStream_t stream) {
  const float* x    = (const float*)d_in[0];
  const int*   ei   = (const int*)d_in[1];
  const int*   bat  = (const int*)d_in[2];
  const float* Wf   = (const float*)d_in[3];
  const float* bf   = (const float*)d_in[4];
  const float* g1   = (const float*)d_in[5];
  const float* be1  = (const float*)d_in[6];
  const float* Wl0  = (const float*)d_in[7];
  const float* bl0  = (const float*)d_in[8];
  const float* Wc   = (const float*)d_in[9];
  const float* bc   = (const float*)d_in[10];
  const float* g2   = (const float*)d_in[11];
  const float* be2  = (const float*)d_in[12];
  const float* Wl1  = (const float*)d_in[13];
  const float* bl1  = (const float*)d_in[14];

  float* out   = (float*)d_out;
  float* wsi   = out;                 // [8,4]
  float* npred = out + GG * TT;       // [N,4]

  float*    ws     = (float*)d_ws;
  float*    hbuf   = ws;                              // N*H fp32 (h1, then h2)
  ushort_t* fbf    = (ushort_t*)(hbuf + (size_t)NN * HH);  // N*H bf16
  ushort_t* gbf    = fbf + (size_t)NN * HH;           // N*H bf16
  float*    stats1 = (float*)(gbf + (size_t)NN * HH); // 256
  float*    stats2 = stats1 + 256;                    // 256
  float*    maxb   = stats2 + 256;                    // 64
  int*      deg      = (int*)(maxb + 64);             // N
  int*      rowstart = deg + NN;                      // N
  int*      cursor   = rowstart + NN;                 // N
  int*      bsum     = cursor + NN;                   // 128
  int*      bscan    = bsum + 128;                    // 128
  int*      srcl     = bscan + 128;                   // NE
  ushort_t* Wbf      = (ushort_t*)(srcl + NE);        // DF*HH
  ushort_t* Wbf2     = Wbf + DF * HH;                 // HH*HH

  hipMemsetAsync(deg, 0, NN * sizeof(int), stream);
  k_init<<<dim3(1), dim3(512), 0, stream>>>(stats1, maxb);
  k_prep<<<dim3(64), dim3(256), 0, stream>>>(Wf, Wbf, DF * HH);
  k_prep<<<dim3(16), dim3(256), 0, stream>>>(Wc, Wbf2, HH * HH);

  // CSR build
  k_count<<<dim3(1024), dim3(256), 0, stream>>>(ei, deg);
  k_scanA<<<dim3(NB_SCAN), dim3(256), 0, stream>>>(deg, rowstart, bsum);
  k_scanB<<<dim3(1), dim3(128), 0, stream>>>(bsum, bscan);
  k_scanC<<<dim3(NB_SCAN), dim3(256), 0, stream>>>(rowstart, bscan, cursor);
  k_fill<<<dim3(1024), dim3(256), 0, stream>>>(ei, cursor, srcl);

  // Layer 0
  k_gemm1_mfma<<<dim3(512), dim3(256), 0, stream>>>(x, Wbf, bf, hbuf, stats1);
  k_finalize_bn<<<dim3(1), dim3(64), 0, stream>>>(stats1, g1, be1, stats1 + 128);
  k_norm_np<1, 0><<<dim3(512), dim3(256), 0, stream>>>(
      hbuf, fbf, stats1 + 128, Wl0, bl0, bat, npred, maxb, (NN + 511) / 512);

  // Layer 1: g = f@Wc, then h2 = g + A.g + b (linearity of GIN)
  k_gemm2_mfma<<<dim3(512), dim3(256), 0, stream>>>(fbf, Wbf2, gbf);
  k_agg<<<dim3(1024), dim3(256), 0, stream>>>(gbf, rowstart, deg, srcl, bc, hbuf, stats2);
  k_finalize_bn<<<dim3(1), dim3(64), 0, stream>>>(stats2, g2, be2, stats2 + 128);
  k_norm_np<0, 1><<<dim3(512), dim3(256), 0, stream>>>(
      hbuf, fbf, stats2 + 128, Wl1, bl1, bat, npred, maxb + 32, (NN + 511) / 512);

  k_wsi<<<dim3(1), dim3(32), 0, stream>>>(maxb, maxb + 32, wsi);
}

// Round 5
// 822.256 us; speedup vs baseline: 1.0142x; 1.0142x over previous
//
#include <hip/hip_runtime.h>
#include <math.h>

#define NN 100000
#define NE 1600000
#define DF 256
#define HH 64
#define TT 4
#define GG 8
#define BN_EPS 1e-5f

#define SCAN_BLK 1024
#define NB_SCAN ((NN + SCAN_BLK - 1) / SCAN_BLK)   // 98

typedef __attribute__((ext_vector_type(8))) short short8v;
typedef __attribute__((ext_vector_type(4))) float f32x4;
typedef unsigned short ushort_t;
typedef unsigned int uint_t;

__device__ __forceinline__ void atomicMaxF(float* addr, float val) {
  if (val >= 0.f) atomicMax((int*)addr, __float_as_int(val));
  else            atomicMin((unsigned int*)addr, __float_as_uint(val));
}

// fp32 -> bf16 bits, round-to-nearest-even
__device__ __forceinline__ short f2bf(float f) {
  uint_t u = __float_as_uint(f);
  u += 0x7FFFu + ((u >> 16) & 1u);
  return (short)(u >> 16);
}
// bf16 pair unpack from uint
__device__ __forceinline__ float bflo(uint_t u) { return __uint_as_float(u << 16); }
__device__ __forceinline__ float bfhi(uint_t u) { return __uint_as_float(u & 0xFFFF0000u); }

// ---------------- init: stats=0, max buffers=-inf ----------------
__global__ void k_init(float* __restrict__ stats, float* __restrict__ maxb) {
  int i = threadIdx.x;
  if (i < 512) stats[i] = 0.f;
  if (i < 64)  maxb[i]  = -INFINITY;
}

// ---------------- prep: fp32 -> bf16 bits ----------------
__global__ void k_prep(const float* __restrict__ W, ushort_t* __restrict__ Wbf, int n) {
  int i = blockIdx.x * 256 + threadIdx.x;
  if (i < n) Wbf[i] = (ushort_t)f2bf(W[i]);
}

// ---------------- GEMM1 (MFMA bf16): h1 = x @ W_first + b, + BN stats ----------------
__global__ __launch_bounds__(256, 2) void k_gemm1_mfma(
    const float* __restrict__ x, const ushort_t* __restrict__ Wbf,
    const float* __restrict__ b, float* __restrict__ h1,
    float* __restrict__ stats) {
  const int lane = threadIdx.x & 63;
  const int li = lane & 15;
  const int lh = lane >> 4;
  const int gw = (blockIdx.x * 256 + (int)threadIdx.x) >> 6;
  const int nw = (gridDim.x * 256) >> 6;

  short8v bf[8][4];
#pragma unroll
  for (int s = 0; s < 8; ++s)
#pragma unroll
    for (int ct = 0; ct < 4; ++ct)
#pragma unroll
      for (int e = 0; e < 8; ++e)
        bf[s][ct][e] = (short)Wbf[(32 * s + 8 * lh + e) * HH + ct * 16 + li];

  float bias[4];
#pragma unroll
  for (int ct = 0; ct < 4; ++ct) bias[ct] = b[ct * 16 + li];

  float ps[4] = {0.f, 0.f, 0.f, 0.f}, pss[4] = {0.f, 0.f, 0.f, 0.f};

  for (int t = gw; t < NN / 16; t += nw) {
    const float* xb = x + (size_t)(t * 16 + li) * DF + 8 * lh;
    f32x4 acc[4];
#pragma unroll
    for (int ct = 0; ct < 4; ++ct) acc[ct] = (f32x4){0.f, 0.f, 0.f, 0.f};

#pragma unroll
    for (int s = 0; s < 8; ++s) {
      float4 a0 = *(const float4*)(xb + 32 * s);
      float4 a1 = *(const float4*)(xb + 32 * s + 4);
      short8v af;
      af[0] = f2bf(a0.x); af[1] = f2bf(a0.y); af[2] = f2bf(a0.z); af[3] = f2bf(a0.w);
      af[4] = f2bf(a1.x); af[5] = f2bf(a1.y); af[6] = f2bf(a1.z); af[7] = f2bf(a1.w);
#pragma unroll
      for (int ct = 0; ct < 4; ++ct)
        acc[ct] = __builtin_amdgcn_mfma_f32_16x16x32_bf16(af, bf[s][ct], acc[ct], 0, 0, 0);
    }

    float* hb = h1 + (size_t)t * 16 * HH;
#pragma unroll
    for (int ct = 0; ct < 4; ++ct) {
#pragma unroll
      for (int r = 0; r < 4; ++r) {
        float h = acc[ct][r] + bias[ct];
        hb[(lh * 4 + r) * HH + ct * 16 + li] = h;
        ps[ct] += h; pss[ct] += h * h;
      }
    }
  }

#pragma unroll
  for (int ct = 0; ct < 4; ++ct) {
    ps[ct]  += __shfl_xor(ps[ct], 16);  ps[ct]  += __shfl_xor(ps[ct], 32);
    pss[ct] += __shfl_xor(pss[ct], 16); pss[ct] += __shfl_xor(pss[ct], 32);
  }
  if (lane < 16) {
#pragma unroll
    for (int ct = 0; ct < 4; ++ct) {
      atomicAdd(&stats[ct * 16 + lane], ps[ct]);
      atomicAdd(&stats[HH + ct * 16 + lane], pss[ct]);
    }
  }
}

// ---------------- BN finalize ----------------
__global__ void k_finalize_bn(const float* __restrict__ sums,
                              const float* __restrict__ gamma,
                              const float* __restrict__ beta,
                              float* __restrict__ ab) {
  int c = threadIdx.x;                                // 64 threads
  float mu  = sums[c] * (1.f / NN);
  float var = sums[HH + c] * (1.f / NN) - mu * mu;
  float a = gamma[c] * rsqrtf(var + BN_EPS);
  ab[c] = a;
  ab[HH + c] = beta[c] - mu * a;
}

// ---------------- normalize+ReLU + head (64->4) + graph max-pool ----------------
// WRITEF: emit f as bf16 (layer 0). ADDOUT: accumulate node_pred (layer 1).
template <int WRITEF, int ADDOUT>
__global__ __launch_bounds__(256) void k_norm_np(
    const float* __restrict__ hin, ushort_t* __restrict__ fout,
    const float* __restrict__ ab, const float* __restrict__ Wlin,
    const float* __restrict__ blin, const int* __restrict__ batch,
    float* __restrict__ node_pred, float* __restrict__ maxbuf, int rpb) {
  __shared__ float lmax[GG * TT];
  if (threadIdx.x < GG * TT) lmax[threadIdx.x] = -INFINITY;
  __syncthreads();

  const int lane = threadIdx.x & 63;
  const int wid  = threadIdx.x >> 6;
  const float a  = ab[lane];
  const float b2 = ab[HH + lane];
  const float4 w = ((const float4*)Wlin)[lane];       // W[lane][0..3]
  const float4 bl = *(const float4*)blin;
  int r0 = blockIdx.x * rpb;
  int r1 = min(r0 + rpb, NN);

  for (int r = r0 + wid; r < r1; r += 4) {
    float h = hin[(size_t)r * HH + lane];
    float f = fmaxf(fmaf(a, h, b2), 0.f);
    if (WRITEF) fout[(size_t)r * HH + lane] = (ushort_t)f2bf(f);
    float p0 = f * w.x, p1 = f * w.y, p2 = f * w.z, p3 = f * w.w;
#pragma unroll
    for (int off = 32; off; off >>= 1) {
      p0 += __shfl_xor(p0, off);
      p1 += __shfl_xor(p1, off);
      p2 += __shfl_xor(p2, off);
      p3 += __shfl_xor(p3, off);
    }
    if (lane == 0) {
      float4 np;
      np.x = p0 + bl.x; np.y = p1 + bl.y; np.z = p2 + bl.z; np.w = p3 + bl.w;
      int g = batch[r];
      atomicMaxF(&lmax[g * TT + 0], np.x);
      atomicMaxF(&lmax[g * TT + 1], np.y);
      atomicMaxF(&lmax[g * TT + 2], np.z);
      atomicMaxF(&lmax[g * TT + 3], np.w);
      float4* op = (float4*)(node_pred + (size_t)r * TT);
      if (ADDOUT) {
        float4 o = *op;
        np.x += o.x; np.y += o.y; np.z += o.z; np.w += o.w;
      }
      *op = np;
    }
  }
  __syncthreads();
  if (threadIdx.x < GG * TT) atomicMaxF(&maxbuf[threadIdx.x], lmax[threadIdx.x]);
}

// ---------------- CSR build: histogram ----------------
__global__ __launch_bounds__(256) void k_count(const int* __restrict__ ei,
                                               int* __restrict__ deg) {
  int i = blockIdx.x * blockDim.x + threadIdx.x;
  int n = gridDim.x * blockDim.x;
  for (int e = i; e < NE; e += n) atomicAdd(&deg[ei[NE + e]], 1);
}

// ---------------- CSR build: 3-kernel exclusive scan ----------------
__global__ __launch_bounds__(256) void k_scanA(const int* __restrict__ deg,
                                               int* __restrict__ rowstart,
                                               int* __restrict__ bsum) {
  __shared__ int s[256];
  int t = threadIdx.x;
  int base = blockIdx.x * SCAN_BLK + t * 4;
  int d0 = 0, d1 = 0, d2 = 0, d3 = 0;
  if (base + 3 < NN) {
    int4 v = *(const int4*)(deg + base);
    d0 = v.x; d1 = v.y; d2 = v.z; d3 = v.w;
  } else {
    if (base + 0 < NN) d0 = deg[base + 0];
    if (base + 1 < NN) d1 = deg[base + 1];
    if (base + 2 < NN) d2 = deg[base + 2];
    if (base + 3 < NN) d3 = deg[base + 3];
  }
  int ts = d0 + d1 + d2 + d3;
  s[t] = ts;
  __syncthreads();
  for (int off = 1; off < 256; off <<= 1) {
    int v = (t >= off) ? s[t - off] : 0;
    __syncthreads();
    s[t] += v;
    __syncthreads();
  }
  int excl = s[t] - ts;                  // block-local exclusive prefix
  if (base + 0 < NN) rowstart[base + 0] = excl;  excl += d0;
  if (base + 1 < NN) rowstart[base + 1] = excl;  excl += d1;
  if (base + 2 < NN) rowstart[base + 2] = excl;  excl += d2;
  if (base + 3 < NN) rowstart[base + 3] = excl;
  if (t == 255) bsum[blockIdx.x] = s[255];
}

__global__ void k_scanB(const int* __restrict__ bsum, int* __restrict__ bscan) {
  __shared__ int s[128];
  int t = threadIdx.x;                   // 128 threads
  int v = (t < NB_SCAN) ? bsum[t] : 0;
  s[t] = v;
  __syncthreads();
  for (int off = 1; off < 128; off <<= 1) {
    int u = (t >= off) ? s[t - off] : 0;
    __syncthreads();
    s[t] += u;
    __syncthreads();
  }
  if (t < NB_SCAN) bscan[t] = s[t] - v;
}

__global__ __launch_bounds__(256) void k_scanC(int* __restrict__ rowstart,
                                               const int* __restrict__ bscan,
                                               int* __restrict__ cursor) {
  int off = bscan[blockIdx.x];
  int base = blockIdx.x * SCAN_BLK + threadIdx.x * 4;
#pragma unroll
  for (int j = 0; j < 4; ++j) {
    int i = base + j;
    if (i < NN) {
      int r = rowstart[i] + off;
      rowstart[i] = r;
      cursor[i] = r;
    }
  }
}

// ---------------- CSR build: fill src lists ----------------
__global__ __launch_bounds__(256) void k_fill(const int* __restrict__ ei,
                                              int* __restrict__ cursor,
                                              int* __restrict__ srcl) {
  int i = blockIdx.x * blockDim.x + threadIdx.x;
  int n = gridDim.x * blockDim.x;
  for (int e = i; e < NE; e += n) {
    int src = ei[e];
    int dst = ei[NE + e];
    int p = atomicAdd(&cursor[dst], 1);
    srcl[p] = src;
  }
}

// ---------------- GEMM2 (MFMA bf16): g = f @ W_conv (no bias), bf16 out ----------------
__global__ __launch_bounds__(256) void k_gemm2_mfma(
    const ushort_t* __restrict__ fbf, const ushort_t* __restrict__ Wbf2,
    ushort_t* __restrict__ g) {
  const int lane = threadIdx.x & 63;
  const int li = lane & 15;
  const int lh = lane >> 4;
  const int gw = (blockIdx.x * 256 + (int)threadIdx.x) >> 6;
  const int nw = (gridDim.x * 256) >> 6;

  short8v bfr[2][4];
#pragma unroll
  for (int s = 0; s < 2; ++s)
#pragma unroll
    for (int ct = 0; ct < 4; ++ct)
#pragma unroll
      for (int e = 0; e < 8; ++e)
        bfr[s][ct][e] = (short)Wbf2[(32 * s + 8 * lh + e) * HH + ct * 16 + li];

  for (int t = gw; t < NN / 16; t += nw) {
    const ushort_t* fb = fbf + (size_t)(t * 16 + li) * HH + 8 * lh;
    short8v a0 = *(const short8v*)(fb);
    short8v a1 = *(const short8v*)(fb + 32);
    f32x4 acc[4];
#pragma unroll
    for (int ct = 0; ct < 4; ++ct) {
      acc[ct] = (f32x4){0.f, 0.f, 0.f, 0.f};
      acc[ct] = __builtin_amdgcn_mfma_f32_16x16x32_bf16(a0, bfr[0][ct], acc[ct], 0, 0, 0);
      acc[ct] = __builtin_amdgcn_mfma_f32_16x16x32_bf16(a1, bfr[1][ct], acc[ct], 0, 0, 0);
    }
    ushort_t* gb = g + (size_t)t * 16 * HH;
#pragma unroll
    for (int ct = 0; ct < 4; ++ct)
#pragma unroll
      for (int r = 0; r < 4; ++r)
        gb[(lh * 4 + r) * HH + ct * 16 + li] = (ushort_t)f2bf(acc[ct][r]);
  }
}

// ---------------- aggregate: h2[r] = b + g[r] + sum g[src], + BN stats ----------------
// half-wave per row (32 lanes x uint = 128B bf16 row); 8-deep explicit MLP:
// issue 8 independent index loads, then 8 independent row-gathers, then VALU.
__global__ __launch_bounds__(256) void k_agg(
    const ushort_t* __restrict__ g, const int* __restrict__ rowstart,
    const int* __restrict__ deg, const int* __restrict__ srcl,
    const float* __restrict__ bias, float* __restrict__ h2,
    float* __restrict__ stats) {
  const int lane = threadIdx.x & 63;
  const int hf = lane >> 5;           // which row of the pair
  const int ql = lane & 31;           // column-pair index (cols 2ql, 2ql+1)
  const int gw = (blockIdx.x * 256 + (int)threadIdx.x) >> 6;
  const int nw = (gridDim.x * 256) >> 6;
  const float2 bb = ((const float2*)bias)[ql];
  const uint_t* grow = (const uint_t*)g + ql;   // row r -> grow[r*32]

  float psx = 0.f, psy = 0.f, pqx = 0.f, pqy = 0.f;

  for (int rb = gw * 2; rb < NN; rb += nw * 2) {
    int row = rb + hf;
    int s0 = rowstart[row];
    int d  = deg[row];
    uint_t sv = grow[(size_t)row * 32];
    float ax = bb.x + bflo(sv);
    float ay = bb.y + bfhi(sv);
    int e = 0;
    while (e + 8 <= d) {
      int i0 = srcl[s0 + e + 0]; int i1 = srcl[s0 + e + 1];
      int i2 = srcl[s0 + e + 2]; int i3 = srcl[s0 + e + 3];
      int i4 = srcl[s0 + e + 4]; int i5 = srcl[s0 + e + 5];
      int i6 = srcl[s0 + e + 6]; int i7 = srcl[s0 + e + 7];
      uint_t v0 = grow[(size_t)i0 * 32];
      uint_t v1 = grow[(size_t)i1 * 32];
      uint_t v2 = grow[(size_t)i2 * 32];
      uint_t v3 = grow[(size_t)i3 * 32];
      uint_t v4 = grow[(size_t)i4 * 32];
      uint_t v5 = grow[(size_t)i5 * 32];
      uint_t v6 = grow[(size_t)i6 * 32];
      uint_t v7 = grow[(size_t)i7 * 32];
      ax += bflo(v0) + bflo(v1) + bflo(v2) + bflo(v3)
          + bflo(v4) + bflo(v5) + bflo(v6) + bflo(v7);
      ay += bfhi(v0) + bfhi(v1) + bfhi(v2) + bfhi(v3)
          + bfhi(v4) + bfhi(v5) + bfhi(v6) + bfhi(v7);
      e += 8;
    }
    if (e + 4 <= d) {
      int i0 = srcl[s0 + e + 0]; int i1 = srcl[s0 + e + 1];
      int i2 = srcl[s0 + e + 2]; int i3 = srcl[s0 + e + 3];
      uint_t v0 = grow[(size_t)i0 * 32];
      uint_t v1 = grow[(size_t)i1 * 32];
      uint_t v2 = grow[(size_t)i2 * 32];
      uint_t v3 = grow[(size_t)i3 * 32];
      ax += bflo(v0) + bflo(v1) + bflo(v2) + bflo(v3);
      ay += bfhi(v0) + bfhi(v1) + bfhi(v2) + bfhi(v3);
      e += 4;
    }
    if (e + 2 <= d) {
      int i0 = srcl[s0 + e + 0]; int i1 = srcl[s0 + e + 1];
      uint_t v0 = grow[(size_t)i0 * 32];
      uint_t v1 = grow[(size_t)i1 * 32];
      ax += bflo(v0) + bflo(v1);
      ay += bfhi(v0) + bfhi(v1);
      e += 2;
    }
    if (e < d) {
      int i0 = srcl[s0 + e];
      uint_t v0 = grow[(size_t)i0 * 32];
      ax += bflo(v0);
      ay += bfhi(v0);
    }
    float2 o; o.x = ax; o.y = ay;
    *(float2*)(h2 + (size_t)row * HH + ql * 2) = o;
    psx += ax; psy += ay; pqx += ax * ax; pqy += ay * ay;
  }

  psx += __shfl_xor(psx, 32); psy += __shfl_xor(psy, 32);
  pqx += __shfl_xor(pqx, 32); pqy += __shfl_xor(pqy, 32);
  if (lane < 32) {
    atomicAdd(&stats[ql * 2 + 0], psx);
    atomicAdd(&stats[ql * 2 + 1], psy);
    atomicAdd(&stats[HH + ql * 2 + 0], pqx);
    atomicAdd(&stats[HH + ql * 2 + 1], pqy);
  }
}

// ---------------- final: wsi = max0 + max1 ----------------
__global__ void k_wsi(const float* __restrict__ m0, const float* __restrict__ m1,
                      float* __restrict__ out) {
  int i = threadIdx.x;                                // 32 threads
  out[i] = m0[i] + m1[i];
}

extern "C" void kernel_launch(void* const* d_in, const int* in_sizes, int n_in,
                              void* d_out, int out_size, void* d_ws, size_t ws_size,
                              hipStream_t stream) {
  const float* x    = (const float*)d_in[0];
  const int*   ei   = (const int*)d_in[1];
  const int*   bat  = (const int*)d_in[2];
  const float* Wf   = (const float*)d_in[3];
  const float* bf   = (const float*)d_in[4];
  const float* g1   = (const float*)d_in[5];
  const float* be1  = (const float*)d_in[6];
  const float* Wl0  = (const float*)d_in[7];
  const float* bl0  = (const float*)d_in[8];
  const float* Wc   = (const float*)d_in[9];
  const float* bc   = (const float*)d_in[10];
  const float* g2   = (const float*)d_in[11];
  const float* be2  = (const float*)d_in[12];
  const float* Wl1  = (const float*)d_in[13];
  const float* bl1  = (const float*)d_in[14];

  float* out   = (float*)d_out;
  float* wsi   = out;                 // [8,4]
  float* npred = out + GG * TT;       // [N,4]

  float*    ws     = (float*)d_ws;
  float*    hbuf   = ws;                              // N*H fp32 (h1, then h2)
  ushort_t* fbf    = (ushort_t*)(hbuf + (size_t)NN * HH);  // N*H bf16
  ushort_t* gbf    = fbf + (size_t)NN * HH;           // N*H bf16
  float*    stats1 = (float*)(gbf + (size_t)NN * HH); // 256
  float*    stats2 = stats1 + 256;                    // 256
  float*    maxb   = stats2 + 256;                    // 64
  int*      deg      = (int*)(maxb + 64);             // N
  int*      rowstart = deg + NN;                      // N
  int*      cursor   = rowstart + NN;                 // N
  int*      bsum     = cursor + NN;                   // 128
  int*      bscan    = bsum + 128;                    // 128
  int*      srcl     = bscan + 128;                   // NE
  ushort_t* Wbf      = (ushort_t*)(srcl + NE);        // DF*HH
  ushort_t* Wbf2     = Wbf + DF * HH;                 // HH*HH

  hipMemsetAsync(deg, 0, NN * sizeof(int), stream);
  k_init<<<dim3(1), dim3(512), 0, stream>>>(stats1, maxb);
  k_prep<<<dim3(64), dim3(256), 0, stream>>>(Wf, Wbf, DF * HH);
  k_prep<<<dim3(16), dim3(256), 0, stream>>>(Wc, Wbf2, HH * HH);

  // CSR build
  k_count<<<dim3(1024), dim3(256), 0, stream>>>(ei, deg);
  k_scanA<<<dim3(NB_SCAN), dim3(256), 0, stream>>>(deg, rowstart, bsum);
  k_scanB<<<dim3(1), dim3(128), 0, stream>>>(bsum, bscan);
  k_scanC<<<dim3(NB_SCAN), dim3(256), 0, stream>>>(rowstart, bscan, cursor);
  k_fill<<<dim3(1024), dim3(256), 0, stream>>>(ei, cursor, srcl);

  // Layer 0
  k_gemm1_mfma<<<dim3(512), dim3(256), 0, stream>>>(x, Wbf, bf, hbuf, stats1);
  k_finalize_bn<<<dim3(1), dim3(64), 0, stream>>>(stats1, g1, be1, stats1 + 128);
  k_norm_np<1, 0><<<dim3(512), dim3(256), 0, stream>>>(
      hbuf, fbf, stats1 + 128, Wl0, bl0, bat, npred, maxb, (NN + 511) / 512);

  // Layer 1: g = f@Wc, then h2 = g + A.g + b (linearity of GIN)
  k_gemm2_mfma<<<dim3(512), dim3(256), 0, stream>>>(fbf, Wbf2, gbf);
  k_agg<<<dim3(2048), dim3(256), 0, stream>>>(gbf, rowstart, deg, srcl, bc, hbuf, stats2);
  k_finalize_bn<<<dim3(1), dim3(64), 0, stream>>>(stats2, g2, be2, stats2 + 128);
  k_norm_np<0, 1><<<dim3(512), dim3(256), 0, stream>>>(
      hbuf, fbf, stats2 + 128, Wl1, bl1, bat, npred, maxb + 32, (NN + 511) / 512);

  k_wsi<<<dim3(1), dim3(32), 0, stream>>>(maxb, maxb + 32, wsi);
}